// Round 1
// baseline (576.842 us; speedup 1.0000x reference)
//
#include <hip/hip_runtime.h>
#include <hip/hip_bf16.h>
#include <cstdint>

typedef __attribute__((ext_vector_type(8))) __bf16 bf16x8;
typedef __attribute__((ext_vector_type(4))) float f32x4;

#define IN_F 4096
#define OUT_F 4096
#define N_TOK 8192
#define NUM_FREQ 16

// ---------- helpers ----------

__device__ inline unsigned short bf16_rne(float f) {
    unsigned int u = __builtin_bit_cast(unsigned int, f);
    unsigned int lsb = (u >> 16) & 1u;
    u += 0x7fffu + lsb;
    return (unsigned short)(u >> 16);
}

__device__ inline float fast_tanh(float x) {
    float ax = fabsf(x);
    float e = __expf(2.0f * ax);
    float t = 1.0f - 2.0f / (e + 1.0f);
    return copysignf(t, x);
}

__device__ inline void load_lds16(const void* g, void* l) {
    __builtin_amdgcn_global_load_lds(
        (const __attribute__((address_space(1))) void*)(uintptr_t)g,
        (__attribute__((address_space(3))) void*)(uint32_t)(uintptr_t)l,
        16, 0, 0);
}

// ---------- kernel 1: W synthesis (fp32 math -> bf16) ----------
// W[o][i] = sa*std*tanh( sum_k amp[k]*sin(r_o*rf_k+rp_k)*cos(c_i*cf_k+cp_k) )
//         + sb*std*tanh( A[o][0]*B[0][i] + A[o][1]*B[1][i] )
__global__ __launch_bounds__(256)
void synth_w(const float* __restrict__ amp, const float* __restrict__ rf,
             const float* __restrict__ cf, const float* __restrict__ rp,
             const float* __restrict__ cp, const float* __restrict__ lA,
             const float* __restrict__ lB, const float* __restrict__ alpha,
             const float* __restrict__ beta, unsigned short* __restrict__ Wb) {
    const int o = blockIdx.x;
    const int tid = threadIdx.x;
    __shared__ float s_s[NUM_FREQ], s_cf[NUM_FREQ], s_cp[NUM_FREQ];
    const float step = 6.28318530717958647692f / 4095.0f;
    if (tid < NUM_FREQ) {
        float r = step * (float)o;
        s_s[tid] = amp[tid] * __sinf(r * rf[tid] + rp[tid]);
        s_cf[tid] = cf[tid];
        s_cp[tid] = cp[tid];
    }
    __syncthreads();
    const float sa = 1.0f / (1.0f + __expf(-alpha[0]));
    const float sb = 1.0f / (1.0f + __expf(-beta[0]));
    const float stdv = 0.015625f;  // sqrt(2/(4096+4096)) = 1/64 exactly
    const float a0 = lA[o * 2 + 0];
    const float a1 = lA[o * 2 + 1];
    unsigned short* row = Wb + (size_t)o * IN_F;

    for (int j = 0; j < 16; ++j) {
        int i = j * 256 + tid;
        float ci = step * (float)i;
        float wf = 0.0f;
#pragma unroll
        for (int k = 0; k < NUM_FREQ; ++k)
            wf += s_s[k] * __cosf(ci * s_cf[k] + s_cp[k]);
        float wl = a0 * lB[i] + a1 * lB[IN_F + i];
        float w = sa * stdv * fast_tanh(wf) + sb * stdv * fast_tanh(wl);
        row[i] = bf16_rne(w);
    }
}

// ---------- kernel 2: cast x fp32 -> bf16 ----------
__global__ __launch_bounds__(256)
void cast_x(const float* __restrict__ x, unsigned short* __restrict__ xb) {
    const size_t idx = ((size_t)blockIdx.x * 256 + threadIdx.x) * 8;
    f32x4 v0 = *(const f32x4*)(x + idx);
    f32x4 v1 = *(const f32x4*)(x + idx + 4);
    union {
        unsigned short u[8];
        f32x4 dummy;
    } r;
#pragma unroll
    for (int k = 0; k < 4; ++k) r.u[k] = bf16_rne(v0[k]);
#pragma unroll
    for (int k = 0; k < 4; ++k) r.u[4 + k] = bf16_rne(v1[k]);
    *(uint4*)(xb + idx) = *(const uint4*)r.u;
}

// ---------- kernel 3: bf16 MFMA GEMM, C = A @ B^T + bias ----------
// A: [M][K] bf16 row-major (x), B: [N][K] bf16 row-major (W), C: [M][N] fp32
#define BM 128
#define BN 128
#define BK 32

__global__ __launch_bounds__(256, 2)
void gemm_bt_bias(const unsigned short* __restrict__ A,
                  const unsigned short* __restrict__ B,
                  const float* __restrict__ bias, float* __restrict__ C,
                  int M, int N, int K) {
    __shared__ unsigned short sA[BM * BK];
    __shared__ unsigned short sB[BN * BK];

    const int tid = threadIdx.x;
    const int wave = tid >> 6;
    const int lane = tid & 63;

    const int bm = blockIdx.y * BM;
    const int bn = blockIdx.x * BN;

    // staging: each global_load_lds call = 256 lanes? No: per-wave, 64 lanes x 16B
    // row covered by lane: wave*16 + (lane>>2); col-quad: (lane&3)*8 elements
    const int srow = wave * 16 + (lane >> 2);
    const int scol = (lane & 3) * 8;

    const unsigned short* gA0 = A + (size_t)(bm + srow) * K + scol;
    const unsigned short* gA1 = A + (size_t)(bm + 64 + srow) * K + scol;
    const unsigned short* gB0 = B + (size_t)(bn + srow) * K + scol;
    const unsigned short* gB1 = B + (size_t)(bn + 64 + srow) * K + scol;

    unsigned short* lA0 = &sA[(wave * 16) * BK];
    unsigned short* lA1 = &sA[(64 + wave * 16) * BK];
    unsigned short* lB0 = &sB[(wave * 16) * BK];
    unsigned short* lB1 = &sB[(64 + wave * 16) * BK];

    const int wm = (wave & 1) * 64;   // wave M offset in tile
    const int wn = (wave >> 1) * 64;  // wave N offset in tile
    const int lm = lane & 15;
    const int quad = lane >> 4;

    f32x4 acc[4][4] = {};

    for (int k0 = 0; k0 < K; k0 += BK) {
        load_lds16(gA0 + k0, lA0);
        load_lds16(gA1 + k0, lA1);
        load_lds16(gB0 + k0, lB0);
        load_lds16(gB1 + k0, lB1);
        __syncthreads();

        bf16x8 af[4], bf[4];
#pragma unroll
        for (int i = 0; i < 4; ++i)
            af[i] = *(const bf16x8*)&sA[(wm + i * 16 + lm) * BK + quad * 8];
#pragma unroll
        for (int i = 0; i < 4; ++i)
            bf[i] = *(const bf16x8*)&sB[(wn + i * 16 + lm) * BK + quad * 8];

#pragma unroll
        for (int im = 0; im < 4; ++im)
#pragma unroll
            for (int in = 0; in < 4; ++in)
                acc[im][in] = __builtin_amdgcn_mfma_f32_16x16x32_bf16(
                    af[im], bf[in], acc[im][in], 0, 0, 0);

        __syncthreads();
    }

    // epilogue: D layout col = lane&15, row = quad*4 + r
#pragma unroll
    for (int in = 0; in < 4; ++in) {
        const int cn = bn + wn + in * 16 + lm;
        const float bv = bias[cn];
#pragma unroll
        for (int im = 0; im < 4; ++im) {
            const int rm = bm + wm + im * 16 + quad * 4;
#pragma unroll
            for (int r = 0; r < 4; ++r)
                C[(size_t)(rm + r) * N + cn] = acc[im][in][r] + bv;
        }
    }
}

// ---------- launch ----------
extern "C" void kernel_launch(void* const* d_in, const int* in_sizes, int n_in,
                              void* d_out, int out_size, void* d_ws,
                              size_t ws_size, hipStream_t stream) {
    const float* x = (const float*)d_in[0];
    const float* amp = (const float*)d_in[1];
    const float* rf = (const float*)d_in[2];
    const float* cf = (const float*)d_in[3];
    const float* rp = (const float*)d_in[4];
    const float* cp = (const float*)d_in[5];
    const float* lA = (const float*)d_in[6];
    const float* lB = (const float*)d_in[7];
    const float* alpha = (const float*)d_in[8];
    const float* beta = (const float*)d_in[9];
    const float* bias = (const float*)d_in[10];
    float* out = (float*)d_out;

    unsigned short* Wb = (unsigned short*)d_ws;            // 4096*4096 bf16 = 32 MiB
    unsigned short* xb = Wb + (size_t)OUT_F * IN_F;        // 8192*4096 bf16 = 64 MiB

    synth_w<<<OUT_F, 256, 0, stream>>>(amp, rf, cf, rp, cp, lA, lB, alpha, beta, Wb);
    cast_x<<<(N_TOK * IN_F) / (256 * 8), 256, 0, stream>>>(x, xb);
    gemm_bt_bias<<<dim3(IN_F / BN, N_TOK / BM), 256, 0, stream>>>(
        xb, Wb, bias, out, N_TOK, OUT_F, IN_F);
}

// Round 2
// 572.264 us; speedup vs baseline: 1.0080x; 1.0080x over previous
//
#include <hip/hip_runtime.h>
#include <hip/hip_bf16.h>
#include <cstdint>

typedef __attribute__((ext_vector_type(8))) __bf16 bf16x8;
typedef __attribute__((ext_vector_type(4))) float f32x4;

#define IN_F 4096
#define OUT_F 4096
#define N_TOK 8192
#define NUM_FREQ 16

// ---------- helpers ----------

__device__ inline unsigned short bf16_rne(float f) {
    unsigned int u = __builtin_bit_cast(unsigned int, f);
    unsigned int lsb = (u >> 16) & 1u;
    u += 0x7fffu + lsb;
    return (unsigned short)(u >> 16);
}

__device__ inline float fast_tanh(float x) {
    float ax = fabsf(x);
    float e = __expf(2.0f * ax);
    float t = 1.0f - 2.0f / (e + 1.0f);
    return copysignf(t, x);
}

__device__ inline void load_lds16(const void* g, void* l) {
    __builtin_amdgcn_global_load_lds(
        (const __attribute__((address_space(1))) void*)(uintptr_t)g,
        (__attribute__((address_space(3))) void*)(uint32_t)(uintptr_t)l,
        16, 0, 0);
}

// ---------- kernel 1: fused W synthesis + x cast ----------
// blocks [0, OUT_F)            : synth W row o  (trans-pipe bound)
// blocks [OUT_F, OUT_F+16384)  : cast x fp32->bf16 (HBM bound)
// Block-uniform branch; disjoint pipes overlap across CUs/waves.
#define CAST_BLOCKS (N_TOK * IN_F / (256 * 8))

__global__ __launch_bounds__(256)
void prep(const float* __restrict__ x, unsigned short* __restrict__ xb,
          const float* __restrict__ amp, const float* __restrict__ rf,
          const float* __restrict__ cf, const float* __restrict__ rp,
          const float* __restrict__ cp, const float* __restrict__ lA,
          const float* __restrict__ lB, const float* __restrict__ alpha,
          const float* __restrict__ beta, unsigned short* __restrict__ Wb) {
    const int tid = threadIdx.x;
    if (blockIdx.x < OUT_F) {
        // ---- W synthesis ----
        const int o = blockIdx.x;
        __shared__ float s_s[NUM_FREQ], s_cf[NUM_FREQ], s_cp[NUM_FREQ];
        const float step = 6.28318530717958647692f / 4095.0f;
        if (tid < NUM_FREQ) {
            float r = step * (float)o;
            s_s[tid] = amp[tid] * __sinf(r * rf[tid] + rp[tid]);
            s_cf[tid] = cf[tid];
            s_cp[tid] = cp[tid];
        }
        __syncthreads();
        const float sa = 1.0f / (1.0f + __expf(-alpha[0]));
        const float sb = 1.0f / (1.0f + __expf(-beta[0]));
        const float stdv = 0.015625f;  // sqrt(2/8192) = 1/64 exactly
        const float a0 = lA[o * 2 + 0];
        const float a1 = lA[o * 2 + 1];
        unsigned short* row = Wb + (size_t)o * IN_F;
#pragma unroll 4
        for (int j = 0; j < 16; ++j) {
            int i = j * 256 + tid;
            float ci = step * (float)i;
            float wf = 0.0f;
#pragma unroll
            for (int k = 0; k < NUM_FREQ; ++k)
                wf += s_s[k] * __cosf(ci * s_cf[k] + s_cp[k]);
            float wl = a0 * lB[i] + a1 * lB[IN_F + i];
            float w = sa * stdv * fast_tanh(wf) + sb * stdv * fast_tanh(wl);
            row[i] = bf16_rne(w);
        }
    } else {
        // ---- x cast ----
        const size_t idx =
            (((size_t)(blockIdx.x - OUT_F)) * 256 + tid) * 8;
        f32x4 v0 = *(const f32x4*)(x + idx);
        f32x4 v1 = *(const f32x4*)(x + idx + 4);
        union {
            unsigned short u[8];
            uint4 q;
        } r;
#pragma unroll
        for (int k = 0; k < 4; ++k) r.u[k] = bf16_rne(v0[k]);
#pragma unroll
        for (int k = 0; k < 4; ++k) r.u[4 + k] = bf16_rne(v1[k]);
        *(uint4*)(xb + idx) = r.q;
    }
}

// ---------- kernel 2: bf16 MFMA GEMM, C = A @ B^T + bias ----------
// A: [M][K] bf16 row-major (x), B: [N][K] bf16 row-major (W), C: [M][N] fp32
// BK=64: halves barrier count vs BK=32 (the vmcnt(0)+barrier drain is the
// diagnosed 47% stall); 32 KB LDS still allows 5 blocks/CU.
#define BM 128
#define BN 128
#define BK 64

__global__ __launch_bounds__(256, 2)
void gemm_bt_bias(const unsigned short* __restrict__ A,
                  const unsigned short* __restrict__ B,
                  const float* __restrict__ bias, float* __restrict__ C,
                  int M, int N, int K) {
    __shared__ unsigned short sA[BM * BK];  // 16 KB
    __shared__ unsigned short sB[BN * BK];  // 16 KB

    const int tid = threadIdx.x;
    const int wave = tid >> 6;
    const int lane = tid & 63;

    const int bm = blockIdx.y * BM;
    const int bn = blockIdx.x * BN;

    // staging: row = 64 shorts = 128 B = 8 lanes x 16 B
    // wave covers 8 rows per call; 4 waves x 8 = 32 rows/call; 4 calls = 128 rows
    const int srow = wave * 8 + (lane >> 3);
    const int scol = (lane & 7) * 8;

    const unsigned short* gA = A + (size_t)(bm + srow) * K + scol;
    const unsigned short* gB = B + (size_t)(bn + srow) * K + scol;
    unsigned short* lA = &sA[(wave * 8) * BK];
    unsigned short* lB = &sB[(wave * 8) * BK];

    const int wm = (wave & 1) * 64;   // wave M offset in tile
    const int wn = (wave >> 1) * 64;  // wave N offset in tile
    const int lm = lane & 15;
    const int quad = lane >> 4;

    f32x4 acc[4][4] = {};

    for (int k0 = 0; k0 < K; k0 += BK) {
#pragma unroll
        for (int r = 0; r < 4; ++r) {
            load_lds16(gA + (size_t)(r * 32) * K + k0, lA + (r * 32) * BK);
            load_lds16(gB + (size_t)(r * 32) * K + k0, lB + (r * 32) * BK);
        }
        __syncthreads();

#pragma unroll
        for (int ks = 0; ks < 2; ++ks) {
            const int kc = ks * 32 + quad * 8;
            bf16x8 af[4], bf[4];
#pragma unroll
            for (int i = 0; i < 4; ++i)
                af[i] = *(const bf16x8*)&sA[(wm + i * 16 + lm) * BK + kc];
#pragma unroll
            for (int i = 0; i < 4; ++i)
                bf[i] = *(const bf16x8*)&sB[(wn + i * 16 + lm) * BK + kc];

#pragma unroll
            for (int im = 0; im < 4; ++im)
#pragma unroll
                for (int in = 0; in < 4; ++in)
                    acc[im][in] = __builtin_amdgcn_mfma_f32_16x16x32_bf16(
                        af[im], bf[in], acc[im][in], 0, 0, 0);
        }

        __syncthreads();
    }

    // epilogue: D layout col = lane&15, row = quad*4 + r
#pragma unroll
    for (int in = 0; in < 4; ++in) {
        const int cn = bn + wn + in * 16 + lm;
        const float bv = bias[cn];
#pragma unroll
        for (int im = 0; im < 4; ++im) {
            const int rm = bm + wm + im * 16 + quad * 4;
#pragma unroll
            for (int r = 0; r < 4; ++r)
                C[(size_t)(rm + r) * N + cn] = acc[im][in][r] + bv;
        }
    }
}

// ---------- launch ----------
extern "C" void kernel_launch(void* const* d_in, const int* in_sizes, int n_in,
                              void* d_out, int out_size, void* d_ws,
                              size_t ws_size, hipStream_t stream) {
    const float* x = (const float*)d_in[0];
    const float* amp = (const float*)d_in[1];
    const float* rf = (const float*)d_in[2];
    const float* cf = (const float*)d_in[3];
    const float* rp = (const float*)d_in[4];
    const float* cp = (const float*)d_in[5];
    const float* lA = (const float*)d_in[6];
    const float* lB = (const float*)d_in[7];
    const float* alpha = (const float*)d_in[8];
    const float* beta = (const float*)d_in[9];
    const float* bias = (const float*)d_in[10];
    float* out = (float*)d_out;

    unsigned short* Wb = (unsigned short*)d_ws;      // 4096*4096 bf16 = 32 MiB
    unsigned short* xb = Wb + (size_t)OUT_F * IN_F;  // 8192*4096 bf16 = 64 MiB

    prep<<<OUT_F + CAST_BLOCKS, 256, 0, stream>>>(
        x, xb, amp, rf, cf, rp, cp, lA, lB, alpha, beta, Wb);
    gemm_bt_bias<<<dim3(IN_F / BN, N_TOK / BM), 256, 0, stream>>>(
        xb, Wb, bias, out, N_TOK, OUT_F, IN_F);
}

// Round 3
// 436.101 us; speedup vs baseline: 1.3227x; 1.3122x over previous
//
#include <hip/hip_runtime.h>
#include <hip/hip_bf16.h>
#include <cstdint>

typedef __attribute__((ext_vector_type(4))) float f32x4;
typedef __attribute__((ext_vector_type(4))) int i32x4;

#define IN_F 4096
#define OUT_F 4096
#define N_TOK 8192
#define NUM_FREQ 16

// ---------- helpers ----------

__device__ inline float fast_tanh(float x) {
    float ax = fabsf(x);
    float e = __expf(2.0f * ax);
    float t = 1.0f - 2.0f / (e + 1.0f);
    return copysignf(t, x);
}

__device__ inline void load_lds16(const void* g, void* l) {
    __builtin_amdgcn_global_load_lds(
        (const __attribute__((address_space(1))) void*)(uintptr_t)g,
        (__attribute__((address_space(3))) void*)(uint32_t)(uintptr_t)l,
        16, 0, 0);
}

__device__ inline int q8(float v, float s) {
    int q = (int)rintf(v * s);
    return min(127, max(-127, q));
}

__device__ inline unsigned int pack4(int q0, int q1, int q2, int q3) {
    return (q0 & 255) | ((q1 & 255) << 8) | ((q2 & 255) << 16) |
           ((q3 & 255) << 24);
}

// ---------- kernel 1: fused W synthesis->i8 + x quantize->i8 ----------
// blocks [0, OUT_F)               : synth W row o, per-row absmax, quantize
// blocks [OUT_F, OUT_F + N_TOK)   : quantize x row t, per-row absmax
__global__ __launch_bounds__(256)
void prep(const float* __restrict__ x, signed char* __restrict__ xq,
          float* __restrict__ sx, const float* __restrict__ amp,
          const float* __restrict__ rf, const float* __restrict__ cf,
          const float* __restrict__ rp, const float* __restrict__ cp,
          const float* __restrict__ lA, const float* __restrict__ lB,
          const float* __restrict__ alpha, const float* __restrict__ beta,
          signed char* __restrict__ wq, float* __restrict__ sw) {
    const int tid = threadIdx.x;
    const int wave = tid >> 6;
    const int lane = tid & 63;
    __shared__ float s_s[NUM_FREQ], s_cf[NUM_FREQ], s_cp[NUM_FREQ];
    __shared__ float red[4];

    if (blockIdx.x < OUT_F) {
        // ---- W synthesis + quantize ----
        const int o = blockIdx.x;
        const float step = 6.28318530717958647692f / 4095.0f;
        if (tid < NUM_FREQ) {
            float r = step * (float)o;
            s_s[tid] = amp[tid] * __sinf(r * rf[tid] + rp[tid]);
            s_cf[tid] = cf[tid];
            s_cp[tid] = cp[tid];
        }
        __syncthreads();
        const float sa = 1.0f / (1.0f + __expf(-alpha[0]));
        const float sb = 1.0f / (1.0f + __expf(-beta[0]));
        const float stdv = 0.015625f;  // sqrt(2/8192) = 1/64 exactly
        const float a0 = lA[o * 2 + 0];
        const float a1 = lA[o * 2 + 1];

        float w[16];
        const int ibase = tid * 16;
        const f32x4* lB4 = (const f32x4*)lB;
#pragma unroll
        for (int g = 0; g < 4; ++g) {
            f32x4 b0 = lB4[tid * 4 + g];
            f32x4 b1 = lB4[1024 + tid * 4 + g];
#pragma unroll
            for (int e = 0; e < 4; ++e) {
                int j = g * 4 + e;
                float ci = step * (float)(ibase + j);
                float wf = 0.0f;
#pragma unroll
                for (int k = 0; k < NUM_FREQ; ++k)
                    wf += s_s[k] * __cosf(ci * s_cf[k] + s_cp[k]);
                float wl = a0 * b0[e] + a1 * b1[e];
                w[j] = sa * stdv * fast_tanh(wf) + sb * stdv * fast_tanh(wl);
            }
        }
        // block absmax reduction
        float m = 0.0f;
#pragma unroll
        for (int j = 0; j < 16; ++j) m = fmaxf(m, fabsf(w[j]));
#pragma unroll
        for (int off = 32; off > 0; off >>= 1)
            m = fmaxf(m, __shfl_xor(m, off));
        if (lane == 0) red[wave] = m;
        __syncthreads();
        m = fmaxf(fmaxf(red[0], red[1]), fmaxf(red[2], red[3]));
        m = fmaxf(m, 1e-20f);
        const float s = 127.0f / m;
        uint4 out;
        unsigned int* op = (unsigned int*)&out;
#pragma unroll
        for (int g = 0; g < 4; ++g)
            op[g] = pack4(q8(w[g * 4], s), q8(w[g * 4 + 1], s),
                          q8(w[g * 4 + 2], s), q8(w[g * 4 + 3], s));
        *(uint4*)(wq + (size_t)o * IN_F + ibase) = out;
        if (tid == 0) sw[o] = m / 127.0f;
    } else {
        // ---- x quantize ----
        const int t = blockIdx.x - OUT_F;
        const f32x4* xr = (const f32x4*)(x + (size_t)t * IN_F);
        f32x4 v[4];
#pragma unroll
        for (int j = 0; j < 4; ++j) v[j] = xr[tid + 256 * j];
        float m = 0.0f;
#pragma unroll
        for (int j = 0; j < 4; ++j)
#pragma unroll
            for (int e = 0; e < 4; ++e) m = fmaxf(m, fabsf(v[j][e]));
#pragma unroll
        for (int off = 32; off > 0; off >>= 1)
            m = fmaxf(m, __shfl_xor(m, off));
        if (lane == 0) red[wave] = m;
        __syncthreads();
        m = fmaxf(fmaxf(red[0], red[1]), fmaxf(red[2], red[3]));
        m = fmaxf(m, 1e-20f);
        const float s = 127.0f / m;
        unsigned int* orow = (unsigned int*)(xq + (size_t)t * IN_F);
#pragma unroll
        for (int j = 0; j < 4; ++j)
            orow[tid + 256 * j] =
                pack4(q8(v[j][0], s), q8(v[j][1], s), q8(v[j][2], s),
                      q8(v[j][3], s));
        if (tid == 0) sx[t] = m / 127.0f;
    }
}

// ---------- kernel 2: i8 MFMA GEMM, C = (sx.sw^T) * (Aq @ Bq^T) + bias ----
// Aq: [M][K] i8 row-major (xq), Bq: [N][K] i8 row-major (wq), C: [M][N] f32
// BK=64 i8 = 64 B/row: byte-identical LDS geometry to the round-1 bf16
// BK=32 kernel (conflict pattern proven), but half the K iterations and
// 2x MFMA rate (mfma_i32_16x16x64_i8).
#define BM 128
#define BN 128
#define BK 64

__global__ __launch_bounds__(256, 2)
void gemm_i8(const signed char* __restrict__ A, const signed char* __restrict__ B,
             const float* __restrict__ sx, const float* __restrict__ sw,
             const float* __restrict__ bias, float* __restrict__ C,
             int M, int N, int K) {
    __shared__ signed char sA[BM * BK];  // 8 KB
    __shared__ signed char sB[BN * BK];  // 8 KB

    const int tid = threadIdx.x;
    const int wave = tid >> 6;
    const int lane = tid & 63;

    const int bm = blockIdx.y * BM;
    const int bn = blockIdx.x * BN;

    // staging: row = 64 B = 4 lanes x 16 B; wave covers 16 rows/call
    const int srow = wave * 16 + (lane >> 2);
    const int scol = (lane & 3) * 16;

    const signed char* gA0 = A + (size_t)(bm + srow) * K + scol;
    const signed char* gA1 = A + (size_t)(bm + 64 + srow) * K + scol;
    const signed char* gB0 = B + (size_t)(bn + srow) * K + scol;
    const signed char* gB1 = B + (size_t)(bn + 64 + srow) * K + scol;

    signed char* lA0 = &sA[(wave * 16) * BK];
    signed char* lA1 = &sA[(64 + wave * 16) * BK];
    signed char* lB0 = &sB[(wave * 16) * BK];
    signed char* lB1 = &sB[(64 + wave * 16) * BK];

    const int wm = (wave & 1) * 64;   // wave M offset in tile
    const int wn = (wave >> 1) * 64;  // wave N offset in tile
    const int lm = lane & 15;
    const int quad = lane >> 4;

    i32x4 acc[4][4] = {};

    for (int k0 = 0; k0 < K; k0 += BK) {
        load_lds16(gA0 + k0, lA0);
        load_lds16(gA1 + k0, lA1);
        load_lds16(gB0 + k0, lB0);
        load_lds16(gB1 + k0, lB1);
        __syncthreads();

        i32x4 af[4], bv[4];
#pragma unroll
        for (int i = 0; i < 4; ++i)
            af[i] = *(const i32x4*)&sA[(wm + i * 16 + lm) * BK + quad * 16];
#pragma unroll
        for (int i = 0; i < 4; ++i)
            bv[i] = *(const i32x4*)&sB[(wn + i * 16 + lm) * BK + quad * 16];

#pragma unroll
        for (int im = 0; im < 4; ++im)
#pragma unroll
            for (int in = 0; in < 4; ++in)
                acc[im][in] = __builtin_amdgcn_mfma_i32_16x16x64_i8(
                    af[im], bv[in], acc[im][in], 0, 0, 0);

        __syncthreads();
    }

    // epilogue: D layout col = lane&15, row = quad*4 + r
    float sxv[4][4];
#pragma unroll
    for (int im = 0; im < 4; ++im)
#pragma unroll
        for (int r = 0; r < 4; ++r)
            sxv[im][r] = sx[bm + wm + im * 16 + quad * 4 + r];

#pragma unroll
    for (int in = 0; in < 4; ++in) {
        const int cn = bn + wn + in * 16 + lm;
        const float bv_ = bias[cn];
        const float scw = sw[cn];
#pragma unroll
        for (int im = 0; im < 4; ++im) {
            const int rm = bm + wm + im * 16 + quad * 4;
#pragma unroll
            for (int r = 0; r < 4; ++r)
                C[(size_t)(rm + r) * N + cn] =
                    (float)acc[im][in][r] * (sxv[im][r] * scw) + bv_;
        }
    }
}

// ---------- launch ----------
extern "C" void kernel_launch(void* const* d_in, const int* in_sizes, int n_in,
                              void* d_out, int out_size, void* d_ws,
                              size_t ws_size, hipStream_t stream) {
    const float* x = (const float*)d_in[0];
    const float* amp = (const float*)d_in[1];
    const float* rf = (const float*)d_in[2];
    const float* cf = (const float*)d_in[3];
    const float* rp = (const float*)d_in[4];
    const float* cp = (const float*)d_in[5];
    const float* lA = (const float*)d_in[6];
    const float* lB = (const float*)d_in[7];
    const float* alpha = (const float*)d_in[8];
    const float* beta = (const float*)d_in[9];
    const float* bias = (const float*)d_in[10];
    float* out = (float*)d_out;

    signed char* wq = (signed char*)d_ws;                       // 16 MiB
    signed char* xq = wq + (size_t)OUT_F * IN_F;                // 32 MiB
    float* sw = (float*)(xq + (size_t)N_TOK * IN_F);            // 16 KiB
    float* sx = sw + OUT_F;                                     // 32 KiB

    prep<<<OUT_F + N_TOK, 256, 0, stream>>>(x, xq, sx, amp, rf, cf, rp, cp,
                                            lA, lB, alpha, beta, wq, sw);
    gemm_i8<<<dim3(OUT_F / BN, N_TOK / BM), 256, 0, stream>>>(
        xq, wq, sx, sw, bias, out, N_TOK, OUT_F, IN_F);
}

// Round 4
// 429.578 us; speedup vs baseline: 1.3428x; 1.0152x over previous
//
#include <hip/hip_runtime.h>
#include <hip/hip_bf16.h>
#include <cstdint>

typedef __attribute__((ext_vector_type(4))) float f32x4;
typedef __attribute__((ext_vector_type(4))) int i32x4;

#define IN_F 4096
#define OUT_F 4096
#define N_TOK 8192
#define NUM_FREQ 16

// ---------- helpers ----------

__device__ inline float fast_tanh(float x) {
    float ax = fabsf(x);
    float e = __expf(2.0f * ax);
    float t = 1.0f - 2.0f / (e + 1.0f);
    return copysignf(t, x);
}

__device__ inline void load_lds16(const void* g, void* l) {
    __builtin_amdgcn_global_load_lds(
        (const __attribute__((address_space(1))) void*)(uintptr_t)g,
        (__attribute__((address_space(3))) void*)(uint32_t)(uintptr_t)l,
        16, 0, 0);
}

__device__ inline int q8(float v, float s) {
    int q = (int)rintf(v * s);
    return min(127, max(-127, q));
}

__device__ inline unsigned int pack4(int q0, int q1, int q2, int q3) {
    return (q0 & 255) | ((q1 & 255) << 8) | ((q2 & 255) << 16) |
           ((q3 & 255) << 24);
}

// ---------- kernel 1: fused W synthesis->i8 + x quantize->i8 ----------
// blocks [0, OUT_F)               : synth W row o, per-row absmax, quantize
// blocks [OUT_F, OUT_F + N_TOK)   : quantize x row t, per-row absmax
__global__ __launch_bounds__(256)
void prep(const float* __restrict__ x, signed char* __restrict__ xq,
          float* __restrict__ sx, const float* __restrict__ amp,
          const float* __restrict__ rf, const float* __restrict__ cf,
          const float* __restrict__ rp, const float* __restrict__ cp,
          const float* __restrict__ lA, const float* __restrict__ lB,
          const float* __restrict__ alpha, const float* __restrict__ beta,
          signed char* __restrict__ wq, float* __restrict__ sw) {
    const int tid = threadIdx.x;
    const int wave = tid >> 6;
    const int lane = tid & 63;
    __shared__ float s_s[NUM_FREQ], s_cf[NUM_FREQ], s_cp[NUM_FREQ];
    __shared__ float red[4];

    if (blockIdx.x < OUT_F) {
        // ---- W synthesis + quantize ----
        const int o = blockIdx.x;
        const float step = 6.28318530717958647692f / 4095.0f;
        if (tid < NUM_FREQ) {
            float r = step * (float)o;
            s_s[tid] = amp[tid] * __sinf(r * rf[tid] + rp[tid]);
            s_cf[tid] = cf[tid];
            s_cp[tid] = cp[tid];
        }
        __syncthreads();
        const float sa = 1.0f / (1.0f + __expf(-alpha[0]));
        const float sb = 1.0f / (1.0f + __expf(-beta[0]));
        const float stdv = 0.015625f;  // sqrt(2/8192) = 1/64 exactly
        const float a0 = lA[o * 2 + 0];
        const float a1 = lA[o * 2 + 1];

        float w[16];
        const int ibase = tid * 16;
        const f32x4* lB4 = (const f32x4*)lB;
#pragma unroll
        for (int g = 0; g < 4; ++g) {
            f32x4 b0 = lB4[tid * 4 + g];
            f32x4 b1 = lB4[1024 + tid * 4 + g];
#pragma unroll
            for (int e = 0; e < 4; ++e) {
                int j = g * 4 + e;
                float ci = step * (float)(ibase + j);
                float wf = 0.0f;
#pragma unroll
                for (int k = 0; k < NUM_FREQ; ++k)
                    wf += s_s[k] * __cosf(ci * s_cf[k] + s_cp[k]);
                float wl = a0 * b0[e] + a1 * b1[e];
                w[j] = sa * stdv * fast_tanh(wf) + sb * stdv * fast_tanh(wl);
            }
        }
        // block absmax reduction
        float m = 0.0f;
#pragma unroll
        for (int j = 0; j < 16; ++j) m = fmaxf(m, fabsf(w[j]));
#pragma unroll
        for (int off = 32; off > 0; off >>= 1)
            m = fmaxf(m, __shfl_xor(m, off));
        if (lane == 0) red[wave] = m;
        __syncthreads();
        m = fmaxf(fmaxf(red[0], red[1]), fmaxf(red[2], red[3]));
        m = fmaxf(m, 1e-20f);
        const float s = 127.0f / m;
        uint4 out;
        unsigned int* op = (unsigned int*)&out;
#pragma unroll
        for (int g = 0; g < 4; ++g)
            op[g] = pack4(q8(w[g * 4], s), q8(w[g * 4 + 1], s),
                          q8(w[g * 4 + 2], s), q8(w[g * 4 + 3], s));
        *(uint4*)(wq + (size_t)o * IN_F + ibase) = out;
        if (tid == 0) sw[o] = m / 127.0f;
    } else {
        // ---- x quantize ----
        const int t = blockIdx.x - OUT_F;
        const f32x4* xr = (const f32x4*)(x + (size_t)t * IN_F);
        f32x4 v[4];
#pragma unroll
        for (int j = 0; j < 4; ++j) v[j] = xr[tid + 256 * j];
        float m = 0.0f;
#pragma unroll
        for (int j = 0; j < 4; ++j)
#pragma unroll
            for (int e = 0; e < 4; ++e) m = fmaxf(m, fabsf(v[j][e]));
#pragma unroll
        for (int off = 32; off > 0; off >>= 1)
            m = fmaxf(m, __shfl_xor(m, off));
        if (lane == 0) red[wave] = m;
        __syncthreads();
        m = fmaxf(fmaxf(red[0], red[1]), fmaxf(red[2], red[3]));
        m = fmaxf(m, 1e-20f);
        const float s = 127.0f / m;
        unsigned int* orow = (unsigned int*)(xq + (size_t)t * IN_F);
#pragma unroll
        for (int j = 0; j < 4; ++j)
            orow[tid + 256 * j] =
                pack4(q8(v[j][0], s), q8(v[j][1], s), q8(v[j][2], s),
                      q8(v[j][3], s));
        if (tid == 0) sx[t] = m / 127.0f;
    }
}

// ---------- kernel 2: i8 MFMA GEMM, C = (sx.sw^T) * (Aq @ Bq^T) + bias ----
// Aq: [M][K] i8 row-major (xq), Bq: [N][K] i8 row-major (wq), C: [M][N] f32
// BK=128 bytes per iteration, SPLIT into two 64B-stride sub-buffers:
//   sA[0] holds k [k0, k0+64), sA[1] holds k [k0+64, k0+128).
// This keeps round-3's proven conflict-free 64B LDS row stride (round-2's
// 128B stride tripled SQ_LDS_BANK_CONFLICT) while halving the barrier
// count (32 K-iters, 32 MFMA per barrier-pair = the AITER ratio).
#define BM 128
#define BN 128
#define BKB 128
#define SUBK 64

__global__ __launch_bounds__(256, 2)
void gemm_i8(const signed char* __restrict__ A, const signed char* __restrict__ B,
             const float* __restrict__ sx, const float* __restrict__ sw,
             const float* __restrict__ bias, float* __restrict__ C,
             int M, int N, int K) {
    __shared__ signed char sA[2][BM * SUBK];  // 2 x 8 KB
    __shared__ signed char sB[2][BN * SUBK];  // 2 x 8 KB

    const int tid = threadIdx.x;
    const int wave = tid >> 6;
    const int lane = tid & 63;

    const int bm = blockIdx.y * BM;
    const int bn = blockIdx.x * BN;

    // staging: row = 64 B = 4 lanes x 16 B; one call covers 16 rows/wave
    const int srow = wave * 16 + (lane >> 2);
    const int scol = (lane & 3) * 16;

    const signed char* gA = A + (size_t)(bm + srow) * K + scol;
    const signed char* gB = B + (size_t)(bn + srow) * K + scol;

    signed char* lA0a = &sA[0][(wave * 16) * SUBK];
    signed char* lA0b = &sA[0][(64 + wave * 16) * SUBK];
    signed char* lA1a = &sA[1][(wave * 16) * SUBK];
    signed char* lA1b = &sA[1][(64 + wave * 16) * SUBK];
    signed char* lB0a = &sB[0][(wave * 16) * SUBK];
    signed char* lB0b = &sB[0][(64 + wave * 16) * SUBK];
    signed char* lB1a = &sB[1][(wave * 16) * SUBK];
    signed char* lB1b = &sB[1][(64 + wave * 16) * SUBK];

    const size_t rowK = (size_t)64 * K;

    const int wm = (wave & 1) * 64;   // wave M offset in tile
    const int wn = (wave >> 1) * 64;  // wave N offset in tile
    const int lm = lane & 15;
    const int quad = lane >> 4;

    i32x4 acc[4][4] = {};

    for (int k0 = 0; k0 < K; k0 += BKB) {
        // sub-buffer 0: k [k0, k0+64)
        load_lds16(gA + k0, lA0a);
        load_lds16(gA + rowK + k0, lA0b);
        load_lds16(gB + k0, lB0a);
        load_lds16(gB + rowK + k0, lB0b);
        // sub-buffer 1: k [k0+64, k0+128)
        load_lds16(gA + k0 + SUBK, lA1a);
        load_lds16(gA + rowK + k0 + SUBK, lA1b);
        load_lds16(gB + k0 + SUBK, lB1a);
        load_lds16(gB + rowK + k0 + SUBK, lB1b);
        __syncthreads();

#pragma unroll
        for (int h = 0; h < 2; ++h) {
            i32x4 af[4], bv[4];
#pragma unroll
            for (int i = 0; i < 4; ++i)
                af[i] = *(const i32x4*)&sA[h][(wm + i * 16 + lm) * SUBK +
                                             quad * 16];
#pragma unroll
            for (int i = 0; i < 4; ++i)
                bv[i] = *(const i32x4*)&sB[h][(wn + i * 16 + lm) * SUBK +
                                              quad * 16];

#pragma unroll
            for (int im = 0; im < 4; ++im)
#pragma unroll
                for (int in = 0; in < 4; ++in)
                    acc[im][in] = __builtin_amdgcn_mfma_i32_16x16x64_i8(
                        af[im], bv[in], acc[im][in], 0, 0, 0);
        }

        __syncthreads();
    }

    // epilogue: D layout col = lane&15, row = quad*4 + r
    float sxv[4][4];
#pragma unroll
    for (int im = 0; im < 4; ++im)
#pragma unroll
        for (int r = 0; r < 4; ++r)
            sxv[im][r] = sx[bm + wm + im * 16 + quad * 4 + r];

#pragma unroll
    for (int in = 0; in < 4; ++in) {
        const int cn = bn + wn + in * 16 + lm;
        const float bv_ = bias[cn];
        const float scw = sw[cn];
#pragma unroll
        for (int im = 0; im < 4; ++im) {
            const int rm = bm + wm + im * 16 + quad * 4;
#pragma unroll
            for (int r = 0; r < 4; ++r)
                C[(size_t)(rm + r) * N + cn] =
                    (float)acc[im][in][r] * (sxv[im][r] * scw) + bv_;
        }
    }
}

// ---------- launch ----------
extern "C" void kernel_launch(void* const* d_in, const int* in_sizes, int n_in,
                              void* d_out, int out_size, void* d_ws,
                              size_t ws_size, hipStream_t stream) {
    const float* x = (const float*)d_in[0];
    const float* amp = (const float*)d_in[1];
    const float* rf = (const float*)d_in[2];
    const float* cf = (const float*)d_in[3];
    const float* rp = (const float*)d_in[4];
    const float* cp = (const float*)d_in[5];
    const float* lA = (const float*)d_in[6];
    const float* lB = (const float*)d_in[7];
    const float* alpha = (const float*)d_in[8];
    const float* beta = (const float*)d_in[9];
    const float* bias = (const float*)d_in[10];
    float* out = (float*)d_out;

    signed char* wq = (signed char*)d_ws;                       // 16 MiB
    signed char* xq = wq + (size_t)OUT_F * IN_F;                // 32 MiB
    float* sw = (float*)(xq + (size_t)N_TOK * IN_F);            // 16 KiB
    float* sx = sw + OUT_F;                                     // 32 KiB

    prep<<<OUT_F + N_TOK, 256, 0, stream>>>(x, xq, sx, amp, rf, cf, rp, cp,
                                            lA, lB, alpha, beta, wq, sw);
    gemm_i8<<<dim3(OUT_F / BN, N_TOK / BM), 256, 0, stream>>>(
        xq, wq, sx, sw, bias, out, N_TOK, OUT_F, IN_F);
}